// Round 7
// baseline (194.682 us; speedup 1.0000x reference)
//
#include <hip/hip_runtime.h>
#include <hip/hip_bf16.h>

#define EMB   1024
#define SEQ   2048
#define BATCH 4
#define NH    16
#define DHEAD 64
#define MROWS (BATCH*SEQ)   // 8192
#define NSTRIP (SEQ/32)     // 64
#define QSCALE 0.18033688011112042f  // 0.125 * log2(e): softmax in exp2 domain

typedef float f32x4  __attribute__((ext_vector_type(4)));
typedef float f32x16 __attribute__((ext_vector_type(16)));
typedef short s16x8  __attribute__((ext_vector_type(8)));

__device__ __forceinline__ f32x4 mfma16(s16x8 a, s16x8 b, f32x4 c) {
    return __builtin_amdgcn_mfma_f32_16x16x32_bf16(a, b, c, 0, 0, 0);
}
__device__ __forceinline__ f32x16 mfma32(s16x8 a, s16x8 b, f32x16 c) {
    return __builtin_amdgcn_mfma_f32_32x32x16_bf16(a, b, c, 0, 0, 0);
}

__device__ __forceinline__ unsigned short f2bf(float f) {
    __hip_bfloat16 h = __float2bfloat16(f);
    return __builtin_bit_cast(unsigned short, h);
}

__device__ __forceinline__ unsigned cvtpk(float lo, float hi) {
    unsigned r;
    asm("v_cvt_pk_bf16_f32 %0, %1, %2" : "=v"(r) : "v"(lo), "v"(hi));
    return r;
}

__device__ __forceinline__ void plane_swap(unsigned &a, unsigned &b) {
    asm("v_permlane32_swap_b32 %0, %1" : "+v"(a), "+v"(b));
}

__device__ __forceinline__ s16x8 frag4(unsigned a, unsigned b, unsigned c, unsigned d) {
    union { unsigned u[4]; s16x8 f; } x;
    x.u[0] = a; x.u[1] = b; x.u[2] = c; x.u[3] = d;
    return x.f;
}

__device__ __forceinline__ float exp2r(float x) {   // raw v_exp_f32 (2^x)
    float r;
    asm("v_exp_f32 %0, %1" : "=v"(r) : "v"(x));
    return r;
}
__device__ __forceinline__ float max3f(float a, float b, float c) {
    float r;
    asm("v_max3_f32 %0, %1, %2, %3" : "=v"(r) : "v"(a), "v"(b), "v"(c));
    return r;
}

// ---------------- fp32 -> bf16 conversion ----------------
__global__ void cvt_bf16(const float* __restrict__ in, unsigned short* __restrict__ out, int n4) {
    int i = blockIdx.x * blockDim.x + threadIdx.x;
    if (i >= n4) return;
    float4 v = reinterpret_cast<const float4*>(in)[i];
    ushort4 o;
    o.x = f2bf(v.x); o.y = f2bf(v.y); o.z = f2bf(v.z); o.w = f2bf(v.w);
    reinterpret_cast<ushort4*>(out)[i] = o;
}

__global__ void cvt_bf16_w(const float* __restrict__ w0, const float* __restrict__ w1,
                           const float* __restrict__ w2, const float* __restrict__ w3,
                           unsigned short* __restrict__ o0, unsigned short* __restrict__ o1,
                           unsigned short* __restrict__ o2, unsigned short* __restrict__ o3,
                           int n4) {
    int i = blockIdx.x * blockDim.x + threadIdx.x;
    if (i >= n4) return;
    const float* in; unsigned short* out;
    switch (blockIdx.y) {
        case 0:  in = w0; out = o0; break;
        case 1:  in = w1; out = o1; break;
        case 2:  in = w2; out = o2; break;
        default: in = w3; out = o3; break;
    }
    float4 v = reinterpret_cast<const float4*>(in)[i];
    ushort4 o;
    o.x = f2bf(v.x); o.y = f2bf(v.y); o.z = f2bf(v.z); o.w = f2bf(v.w);
    reinterpret_cast<ushort4*>(out)[i] = o;
}

#define GLDS(g, s) __builtin_amdgcn_global_load_lds((const __attribute__((address_space(1))) void*)(g), \
                       (__attribute__((address_space(3))) void*)(s), 16, 0, 0)

// ================= 8-phase counted-vmcnt GEMM core =================
// BM=256, BN=128, BK=64.  512 threads = 8 waves (wm=w&3 over M, wn=w>>2 over N),
// per-wave 64x64 output (acc[4][4] of 16x16 frags).
// LDS per K-tile: A = 4 k16-slice units (8KB: [256 rows][2x16B]),
//                 B = 2 k32 units (8KB: [kslice2][128 rows][2x16B]).  x2 dbuf = 96KB.
// Stage order per tile t (staging t+1): p0:A0  p1:A1,B0  p2:A2  p3:A3,B1.
// vmcnt(3) at end of p1 and p3 => group needed next is landed; never drains in-flight prefetch.
// Both-sides XOR swizzle: byte4 ^= row-bit2 (pre-swizzled global source).
#define MEMF asm volatile("" ::: "memory")
#define SBAR __builtin_amdgcn_s_barrier()

#define STA_(buf, kb, s) GLDS(Ag + (kb) + (s)*16, (buf) + (s)*8192 + wbase)
#define STB_(buf, kb, u) GLDS(Bg + (kb) + (u)*32, (buf) + (u)*8192 + wbase)
#define LDA_(buf, ks, mi) (*(const s16x8*)((buf) + (ks)*16384 + (lg>>1)*8192 + \
        (wm*64 + (mi)*16 + lr)*32 + (((lg&1) ^ rdsw))*16))
#define LDB_(buf, ks, ni) (*(const s16x8*)((buf) + (ks)*8192 + (lg>>1)*4096 + \
        (wn*64 + (ni)*16 + lr)*32 + (((lg&1) ^ rdsw))*16))

#define MMGRP(MH) \
    if constexpr (SWAP) { \
        acc[0][MH]     = mfma16(q0, af0, acc[0][MH]); \
        acc[1][MH]     = mfma16(q1, af0, acc[1][MH]); \
        acc[2][MH]     = mfma16(q2, af0, acc[2][MH]); \
        acc[3][MH]     = mfma16(q3, af0, acc[3][MH]); \
        acc[0][(MH)+1] = mfma16(q0, af1, acc[0][(MH)+1]); \
        acc[1][(MH)+1] = mfma16(q1, af1, acc[1][(MH)+1]); \
        acc[2][(MH)+1] = mfma16(q2, af1, acc[2][(MH)+1]); \
        acc[3][(MH)+1] = mfma16(q3, af1, acc[3][(MH)+1]); \
    } else { \
        acc[MH][0]     = mfma16(af0, q0, acc[MH][0]); \
        acc[MH][1]     = mfma16(af0, q1, acc[MH][1]); \
        acc[MH][2]     = mfma16(af0, q2, acc[MH][2]); \
        acc[MH][3]     = mfma16(af0, q3, acc[MH][3]); \
        acc[(MH)+1][0] = mfma16(af1, q0, acc[(MH)+1][0]); \
        acc[(MH)+1][1] = mfma16(af1, q1, acc[(MH)+1][1]); \
        acc[(MH)+1][2] = mfma16(af1, q2, acc[(MH)+1][2]); \
        acc[(MH)+1][3] = mfma16(af1, q3, acc[(MH)+1][3]); \
    }

#define TILE_(CA, CB, NA, NB, KBN, STG) { \
    /* p0: ks=0, acc rows 0-1 */ \
    s16x8 q0 = LDB_(CB,0,0), q1 = LDB_(CB,0,1), q2 = LDB_(CB,0,2), q3 = LDB_(CB,0,3); \
    s16x8 af0 = LDA_(CA,0,0), af1 = LDA_(CA,0,1); \
    if (STG) { STA_(NA, KBN, 0); } \
    MEMF; SBAR; \
    __builtin_amdgcn_s_setprio(1); MMGRP(0); __builtin_amdgcn_s_setprio(0); \
    MEMF; SBAR; MEMF; \
    /* p1: ks=0, acc rows 2-3 */ \
    af0 = LDA_(CA,0,2); af1 = LDA_(CA,0,3); \
    if (STG) { STA_(NA, KBN, 1); STB_(NB, KBN, 0); } \
    MEMF; SBAR; \
    __builtin_amdgcn_s_setprio(1); MMGRP(2); __builtin_amdgcn_s_setprio(0); \
    if (STG) { asm volatile("s_waitcnt vmcnt(3)" ::: "memory"); } \
    else     { asm volatile("s_waitcnt vmcnt(0)" ::: "memory"); } \
    MEMF; SBAR; MEMF; \
    /* p2: ks=1, acc rows 0-1 */ \
    q0 = LDB_(CB,1,0); q1 = LDB_(CB,1,1); q2 = LDB_(CB,1,2); q3 = LDB_(CB,1,3); \
    af0 = LDA_(CA,1,0); af1 = LDA_(CA,1,1); \
    if (STG) { STA_(NA, KBN, 2); } \
    MEMF; SBAR; \
    __builtin_amdgcn_s_setprio(1); MMGRP(0); __builtin_amdgcn_s_setprio(0); \
    MEMF; SBAR; MEMF; \
    /* p3: ks=1, acc rows 2-3 */ \
    af0 = LDA_(CA,1,2); af1 = LDA_(CA,1,3); \
    if (STG) { STA_(NA, KBN, 3); STB_(NB, KBN, 1); } \
    MEMF; SBAR; \
    __builtin_amdgcn_s_setprio(1); MMGRP(2); __builtin_amdgcn_s_setprio(0); \
    if (STG) { asm volatile("s_waitcnt vmcnt(3)" ::: "memory"); } \
    MEMF; SBAR; MEMF; \
}

template<bool SWAP>
__device__ __forceinline__ void gemm8p_core(const unsigned short* __restrict__ A,
                                            const unsigned short* __restrict__ Bw,
                                            int mBase, int nBase,
                                            f32x4 (&acc)[4][4], char* lds)
{
    const int tid = threadIdx.x;
    const int w = tid >> 6, l = tid & 63;
    const int lg = l >> 4, lr = l & 15;
    const int wm = w & 3, wn = w >> 2;
    char* const A0 = lds;
    char* const A1 = lds + 32768;
    char* const B0 = lds + 65536;
    char* const B1 = lds + 81920;
    const int wbase = w * 1024;
    const int rdsw = (lr >> 2) & 1;                 // read-side swizzle bit (row bit2)
    const int swz  = (tid >> 3) & 1;                // stage-side: row bit2
    const int skh  = (tid & 1) ^ swz;               // pre-swizzled k-octet
    const unsigned short* Ag = A  + (size_t)(mBase + (tid >> 1)) * EMB + skh * 8;
    const unsigned short* Bg = Bw + (size_t)(nBase + ((tid >> 1) & 127)) * EMB
                                  + (tid >> 8) * 16 + skh * 8;

    // prologue: stage tile 0 (order: A0,A1,B0,A2,A3,B1), wait for group1 only
    STA_(A0, 0, 0); STA_(A0, 0, 1); STB_(B0, 0, 0);
    STA_(A0, 0, 2); STA_(A0, 0, 3); STB_(B0, 0, 1);
    asm volatile("s_waitcnt vmcnt(3)" ::: "memory");
    SBAR; MEMF;

    for (int t = 0; t < 16; t += 2) {
        TILE_(A0, B0, A1, B1, (t+1)*64, true);
        TILE_(A1, B1, A0, B0, (t+2)*64, (t+2) < 16);
    }
}

// ---------------- fused QKV GEMM (8-phase) ----------------
// grid (24, 32): x = seg*8 + n-tile(128), y = m-tile(256).
__global__ __launch_bounds__(512) void gemm_qkv8(const unsigned short* __restrict__ A,
                                                 const unsigned short* __restrict__ wqb,
                                                 const unsigned short* __restrict__ wkb,
                                                 const unsigned short* __restrict__ wvb,
                                                 const float* __restrict__ bq,
                                                 const float* __restrict__ bk,
                                                 const float* __restrict__ bv,
                                                 unsigned short* __restrict__ qB,
                                                 unsigned short* __restrict__ kB,
                                                 unsigned short* __restrict__ vtB) {
    __shared__ __align__(16) char lds[98304];
    const int nb  = blockIdx.x;
    const int seg = nb >> 3;
    const int mBase = blockIdx.y * 256;
    const int nBase = (nb & 7) * 128;
    const unsigned short* Bw = (seg == 0) ? wqb : (seg == 1) ? wkb : wvb;
    const float* bias = (seg == 0) ? bq : (seg == 1) ? bk : bv;

    const int tid = threadIdx.x;
    const int w = tid >> 6, l = tid & 63;
    const int lg = l >> 4, lr = l & 15;
    const int wm = w & 3, wn = w >> 2;

    f32x4 acc[4][4] = {};
    if (seg == 2) gemm8p_core<true >(A, Bw, mBase, nBase, acc, lds);
    else          gemm8p_core<false>(A, Bw, mBase, nBase, acc, lds);

    const int colBase = nBase + wn * 64;
    const int rowBase = mBase + wm * 64;
    if (seg != 2) {
        unsigned short* outp = seg ? kB : qB;
        const float oscale = seg ? 1.0f : QSCALE;
        #pragma unroll
        for (int ni = 0; ni < 4; ++ni) {
            const int col = colBase + ni*16 + lr;
            const float bv = bias[col];
            const int h = col >> 6, d = col & 63;
            const int inner = ((d >> 4) * 2 + ((d >> 3) & 1)) * 256 + (d & 7);
            #pragma unroll
            for (int mi = 0; mi < 4; ++mi) {
                #pragma unroll
                for (int r = 0; r < 4; ++r) {
                    const int gr = rowBase + mi*16 + lg*4 + r;
                    const int b = gr >> 11, sin_ = gr & 2047;
                    const int strip = sin_ >> 5, l31q = sin_ & 31;
                    outp[(size_t)(b*NH + h) * (SEQ*DHEAD) + strip*2048 + inner + l31q*8]
                        = f2bf((acc[mi][ni][r] + bv) * oscale);
                }
            }
        }
    } else {
        #pragma unroll
        for (int ni = 0; ni < 4; ++ni) {
            #pragma unroll
            for (int r = 0; r < 4; ++r) {
                const int n = colBase + ni*16 + lg*4 + r;
                const float bv = bias[n];
                const int h = n >> 6, d = n & 63;
                #pragma unroll
                for (int mi = 0; mi < 4; ++mi) {
                    const int tok = rowBase + mi*16 + lr;
                    const int b = tok >> 11, sv = tok & 2047;
                    const int kvt = sv >> 5, ks = (sv >> 4) & 1, hi2 = (sv >> 3) & 1, j = sv & 7;
                    vtB[(size_t)(b*NH + h) * (SEQ*DHEAD) + kvt*2048 + (ks*2 + hi2)*512 + d*8 + j]
                        = f2bf(acc[ni][mi][r] + bv);
                }
            }
        }
    }
}

// ---------------- output projection GEMM (8-phase, fp32 out + bias) ----------------
// grid (8, 32)
__global__ __launch_bounds__(512) void gemm_out8(const unsigned short* __restrict__ A,
                                                 const unsigned short* __restrict__ Bw,
                                                 const float* __restrict__ bias,
                                                 float* __restrict__ Out) {
    __shared__ __align__(16) char lds[98304];
    const int mBase = blockIdx.y * 256;
    const int nBase = blockIdx.x * 128;
    const int tid = threadIdx.x;
    const int w = tid >> 6, l = tid & 63;
    const int lg = l >> 4, lr = l & 15;
    const int wm = w & 3, wn = w >> 2;

    f32x4 acc[4][4] = {};
    gemm8p_core<false>(A, Bw, mBase, nBase, acc, lds);

    const int colBase = nBase + wn * 64;
    const int rowBase = mBase + wm * 64;
    #pragma unroll
    for (int ni = 0; ni < 4; ++ni) {
        const int col = colBase + ni*16 + lr;
        const float bv = bias[col];
        #pragma unroll
        for (int mi = 0; mi < 4; ++mi) {
            #pragma unroll
            for (int r = 0; r < 4; ++r) {
                const int gr = rowBase + mi*16 + lg*4 + r;
                Out[(size_t)gr * EMB + col] = acc[mi][ni][r] + bv;
            }
        }
    }
}

// ---------------- flash attention (causal), swapped-operand 32x32 MFMA ----------------
__global__ __launch_bounds__(64) void attn_fwd(const unsigned short* __restrict__ qb,
                                               const unsigned short* __restrict__ kb,
                                               const unsigned short* __restrict__ vb,
                                               unsigned short* __restrict__ ctx) {
    __shared__ __align__(16) unsigned sld[32*36];
    const int l = threadIdx.x;
    const int l31 = l & 31, hi = l >> 5;
    const int bh = blockIdx.x & 63;
    const int strip = (NSTRIP - 1) - ((int)blockIdx.x >> 6);   // mixes depth across CUs
    const int q0 = strip * 32;
    const size_t hbase = (size_t)bh * SEQ * DHEAD;
    const unsigned short* qh = qb + hbase;
    const unsigned short* kh = kb + hbase;
    const unsigned short* vh = vb + hbase;

    s16x8 qf[4];
    #pragma unroll
    for (int s = 0; s < 4; ++s)
        qf[s] = *reinterpret_cast<const s16x8*>(&qh[strip*2048 + s*512 + l*8]);

    f32x16 o0 = {}, o1 = {};
    float m = -__builtin_inff(), lsum = 0.f;
    const int ntiles = strip + 1;

    s16x8 kfA[4], vfA[4], kfB[4], vfB[4];

    auto LOADKV = [&](s16x8* kf, s16x8* vf, int t) {
        const unsigned short* kp = kh + t*2048;
        #pragma unroll
        for (int s = 0; s < 4; ++s)
            kf[s] = *reinterpret_cast<const s16x8*>(&kp[s*512 + l*8]);
        const unsigned short* vp = vh + t*2048 + hi*512 + l31*8;
        #pragma unroll
        for (int ks = 0; ks < 2; ++ks) {
            vf[ks]     = *reinterpret_cast<const s16x8*>(&vp[ks*1024]);
            vf[2 + ks] = *reinterpret_cast<const s16x8*>(&vp[ks*1024 + 256]);
        }
    };

    auto BODY = [&](s16x8* kf, s16x8* vf, int t) {
        f32x16 sa = {};
        #pragma unroll
        for (int s = 0; s < 4; ++s) sa = mfma32(kf[s], qf[s], sa);

        if (t == strip) {  // diagonal tile: mask kv > q
            #pragma unroll
            for (int r = 0; r < 16; ++r) {
                const int kvloc = (r & 3) + 8*(r >> 2) + 4*hi;
                if (kvloc > l31) sa[r] = -__builtin_inff();
            }
        }

        const float a0 = max3f(sa[0],  sa[1],  sa[2]);
        const float a1 = max3f(sa[3],  sa[4],  sa[5]);
        const float a2 = max3f(sa[6],  sa[7],  sa[8]);
        const float a3 = max3f(sa[9],  sa[10], sa[11]);
        const float a4 = max3f(sa[12], sa[13], sa[14]);
        const float b0 = max3f(a0, a1, a2);
        const float b1 = max3f(a3, a4, sa[15]);
        float pm = fmaxf(b0, b1);
        pm = fmaxf(pm, __shfl_xor(pm, 32));

        float mn = m;
        if (!__all(pm <= m + 8.0f)) {        // T13 defer-max (log2 domain: p <= 256)
            mn = fmaxf(m, pm);
            const float fs = exp2r(m - mn);
            o0 *= fs; o1 *= fs; lsum *= fs;
            m = mn;
        }

        #pragma unroll
        for (int r = 0; r < 16; ++r) sa[r] = exp2r(sa[r] - mn);   // in-place

        const float s0 = sa[0]+sa[1],   s1 = sa[2]+sa[3],   s2 = sa[4]+sa[5],   s3 = sa[6]+sa[7];
        const float s4 = sa[8]+sa[9],   s5 = sa[10]+sa[11], s6 = sa[12]+sa[13], s7 = sa[14]+sa[15];
        const float t0 = s0+s1, t1 = s2+s3, t2 = s4+s5, t3 = s6+s7;
        float rs = (t0+t1) + (t2+t3);
        rs += __shfl_xor(rs, 32);
        lsum += rs;

        unsigned u[4], v[4];
        #pragma unroll
        for (int r2 = 0; r2 < 4; ++r2) {
            u[r2] = cvtpk(sa[4*r2 + 0], sa[4*r2 + 1]);
            v[r2] = cvtpk(sa[4*r2 + 2], sa[4*r2 + 3]);
        }
        plane_swap(u[0], u[1]); plane_swap(v[0], v[1]);
        plane_swap(u[2], u[3]); plane_swap(v[2], v[3]);
        const s16x8 pf0 = frag4(u[0], v[0], u[1], v[1]);
        const s16x8 pf1 = frag4(u[2], v[2], u[3], v[3]);

        o0 = mfma32(vf[0], pf0, o0);
        o0 = mfma32(vf[1], pf1, o0);
        o1 = mfma32(vf[2], pf0, o1);
        o1 = mfma32(vf[3], pf1, o1);
    };

    LOADKV(kfA, vfA, 0);
    int t = 0;
    for (; t + 1 < ntiles; t += 2) {
        LOADKV(kfB, vfB, t + 1);
        BODY(kfA, vfA, t);
        if (t + 2 < ntiles) LOADKV(kfA, vfA, t + 2);
        BODY(kfB, vfB, t + 1);
    }
    if (t < ntiles) BODY(kfA, vfA, t);

    const float inv = 1.0f / lsum;
    #pragma unroll
    for (int dt = 0; dt < 2; ++dt) {
        #pragma unroll
        for (int r2 = 0; r2 < 4; ++r2) {
            const float e0 = (dt ? o1[4*r2+0] : o0[4*r2+0]) * inv;
            const float e1 = (dt ? o1[4*r2+1] : o0[4*r2+1]) * inv;
            const float e2 = (dt ? o1[4*r2+2] : o0[4*r2+2]) * inv;
            const float e3 = (dt ? o1[4*r2+3] : o0[4*r2+3]) * inv;
            const int col = 4*r2 + 2*hi + 16*dt;
            sld[l31*36 + col]     = cvtpk(e0, e1);
            sld[l31*36 + col + 1] = cvtpk(e2, e3);
        }
    }
    asm volatile("s_waitcnt lgkmcnt(0)" ::: "memory");
    __builtin_amdgcn_sched_barrier(0);
    const int row = l >> 1, half = l & 1;
    const unsigned* rp = &sld[row*36 + half*16];
    const int b = bh >> 4, h = bh & 15;
    unsigned short* op = &ctx[((size_t)b*SEQ + q0 + row) * EMB + h*DHEAD + half*32];
    #pragma unroll
    for (int i = 0; i < 4; ++i) {
        uint4 d4 = *reinterpret_cast<const uint4*>(rp + i*4);
        *reinterpret_cast<uint4*>(op + i*8) = d4;
    }
}

// ---------------- launch ----------------
extern "C" void kernel_launch(void* const* d_in, const int* in_sizes, int n_in,
                              void* d_out, int out_size, void* d_ws, size_t ws_size,
                              hipStream_t stream) {
    const float* x  = (const float*)d_in[0];
    const float* wq = (const float*)d_in[1];
    const float* bq = (const float*)d_in[2];
    const float* wk = (const float*)d_in[3];
    const float* bk = (const float*)d_in[4];
    const float* wv = (const float*)d_in[5];
    const float* bv = (const float*)d_in[6];
    const float* wo = (const float*)d_in[7];
    const float* bo = (const float*)d_in[8];
    float* out = (float*)d_out;

    char* ws = (char*)d_ws;
    const size_t MB = 1ull << 20;
    unsigned short* xb  = (unsigned short*)(ws);            // 16 MB; reused as ctx later
    unsigned short* wqb = (unsigned short*)(ws + 16*MB);
    unsigned short* wkb = (unsigned short*)(ws + 18*MB);
    unsigned short* wvb = (unsigned short*)(ws + 20*MB);
    unsigned short* wob = (unsigned short*)(ws + 22*MB);
    unsigned short* qB  = (unsigned short*)(ws + 24*MB);    // fragment-ready, pre-scaled (exp2 domain)
    unsigned short* kB  = (unsigned short*)(ws + 40*MB);    // fragment-ready
    unsigned short* vtB = (unsigned short*)(ws + 56*MB);    // fragment-ready V^T
    unsigned short* ctx = xb;

    const int nx4 = MROWS * EMB / 4;
    const int nw4 = EMB * EMB / 4;
    cvt_bf16<<<(nx4 + 255)/256, 256, 0, stream>>>(x, xb, nx4);
    cvt_bf16_w<<<dim3((nw4 + 255)/256, 4), 256, 0, stream>>>(wq, wk, wv, wo, wqb, wkb, wvb, wob, nw4);

    gemm_qkv8<<<dim3(24, MROWS/256), 512, 0, stream>>>(xb, wqb, wkb, wvb, bq, bk, bv, qB, kB, vtB);

    attn_fwd<<<dim3(NSTRIP * BATCH * NH), 64, 0, stream>>>(qB, kB, vtB, ctx);

    gemm_out8<<<dim3(EMB/128, MROWS/256), 512, 0, stream>>>(ctx, wob, bo, out);
}

// Round 8
// 186.593 us; speedup vs baseline: 1.0434x; 1.0434x over previous
//
#include <hip/hip_runtime.h>
#include <hip/hip_bf16.h>

#define EMB   1024
#define SEQ   2048
#define BATCH 4
#define NH    16
#define DHEAD 64
#define MROWS (BATCH*SEQ)   // 8192
#define NSTRIP (SEQ/32)     // 64
#define QSCALE 0.18033688011112042f  // 0.125 * log2(e): softmax in exp2 domain

typedef float f32x4  __attribute__((ext_vector_type(4)));
typedef float f32x16 __attribute__((ext_vector_type(16)));
typedef short s16x8  __attribute__((ext_vector_type(8)));

__device__ __forceinline__ f32x4 mfma16(s16x8 a, s16x8 b, f32x4 c) {
    return __builtin_amdgcn_mfma_f32_16x16x32_bf16(a, b, c, 0, 0, 0);
}
__device__ __forceinline__ f32x16 mfma32(s16x8 a, s16x8 b, f32x16 c) {
    return __builtin_amdgcn_mfma_f32_32x32x16_bf16(a, b, c, 0, 0, 0);
}

__device__ __forceinline__ unsigned short f2bf(float f) {
    __hip_bfloat16 h = __float2bfloat16(f);
    return __builtin_bit_cast(unsigned short, h);
}

__device__ __forceinline__ unsigned cvtpk(float lo, float hi) {
    unsigned r;
    asm("v_cvt_pk_bf16_f32 %0, %1, %2" : "=v"(r) : "v"(lo), "v"(hi));
    return r;
}

__device__ __forceinline__ void plane_swap(unsigned &a, unsigned &b) {
    asm("v_permlane32_swap_b32 %0, %1" : "+v"(a), "+v"(b));
}

__device__ __forceinline__ s16x8 frag4(unsigned a, unsigned b, unsigned c, unsigned d) {
    union { unsigned u[4]; s16x8 f; } x;
    x.u[0] = a; x.u[1] = b; x.u[2] = c; x.u[3] = d;
    return x.f;
}

__device__ __forceinline__ float exp2r(float x) {   // raw v_exp_f32 (2^x)
    float r;
    asm("v_exp_f32 %0, %1" : "=v"(r) : "v"(x));
    return r;
}
__device__ __forceinline__ float max3f(float a, float b, float c) {
    float r;
    asm("v_max3_f32 %0, %1, %2, %3" : "=v"(r) : "v"(a), "v"(b), "v"(c));
    return r;
}

// ---------------- fp32 -> bf16 conversion ----------------
__global__ void cvt_bf16(const float* __restrict__ in, unsigned short* __restrict__ out, int n4) {
    int i = blockIdx.x * blockDim.x + threadIdx.x;
    if (i >= n4) return;
    float4 v = reinterpret_cast<const float4*>(in)[i];
    ushort4 o;
    o.x = f2bf(v.x); o.y = f2bf(v.y); o.z = f2bf(v.z); o.w = f2bf(v.w);
    reinterpret_cast<ushort4*>(out)[i] = o;
}

__global__ void cvt_bf16_w(const float* __restrict__ w0, const float* __restrict__ w1,
                           const float* __restrict__ w2, const float* __restrict__ w3,
                           unsigned short* __restrict__ o0, unsigned short* __restrict__ o1,
                           unsigned short* __restrict__ o2, unsigned short* __restrict__ o3,
                           int n4) {
    int i = blockIdx.x * blockDim.x + threadIdx.x;
    if (i >= n4) return;
    const float* in; unsigned short* out;
    switch (blockIdx.y) {
        case 0:  in = w0; out = o0; break;
        case 1:  in = w1; out = o1; break;
        case 2:  in = w2; out = o2; break;
        default: in = w3; out = o3; break;
    }
    float4 v = reinterpret_cast<const float4*>(in)[i];
    ushort4 o;
    o.x = f2bf(v.x); o.y = f2bf(v.y); o.z = f2bf(v.z); o.w = f2bf(v.w);
    reinterpret_cast<ushort4*>(out)[i] = o;
}

#define GLDS(g, s) __builtin_amdgcn_global_load_lds((const __attribute__((address_space(1))) void*)(g), \
                       (__attribute__((address_space(3))) void*)(s), 16, 0, 0)

// ================= counted-vmcnt GEMM core, 2 phases / K-tile, 16 MFMA / phase =================
// BM=256, BN=128, BK=64.  512 threads = 8 waves (wm=w&3 over M, wn=w>>2 over N),
// per-wave 64x64 output (acc[4][4] of 16x16 frags).
// LDS per K-tile: A = 4 k16-slice units (8KB each), B = 2 k32 units (8KB each).  x2 dbuf = 96KB.
// Phase p reads k-slice p's units; stages the SAME slice's units for tile t+1 (3 gloads).
// vmcnt(3) at each phase end retires exactly the group needed by the next phase's ds_reads.
// Both-sides XOR swizzle: byte4 ^= row-bit2 (pre-swizzled global source) -> 0 bank conflicts.
#define MEMF asm volatile("" ::: "memory")
#define SBAR __builtin_amdgcn_s_barrier()

#define STA_(buf, kb, s) GLDS(Ag + (kb) + (s)*16, (buf) + (s)*8192 + wbase)
#define STB_(buf, kb, u) GLDS(Bg + (kb) + (u)*32, (buf) + (u)*8192 + wbase)
#define LDA_(buf, ks, mi) (*(const s16x8*)((buf) + (ks)*16384 + (lg>>1)*8192 + \
        (wm*64 + (mi)*16 + lr)*32 + (((lg&1) ^ rdsw))*16))
#define LDB_(buf, ks, ni) (*(const s16x8*)((buf) + (ks)*8192 + (lg>>1)*4096 + \
        (wn*64 + (ni)*16 + lr)*32 + (((lg&1) ^ rdsw))*16))

#define MMGRP16 \
    if constexpr (SWAP) { \
        acc[0][0] = mfma16(q0, af0, acc[0][0]); acc[1][0] = mfma16(q1, af0, acc[1][0]); \
        acc[2][0] = mfma16(q2, af0, acc[2][0]); acc[3][0] = mfma16(q3, af0, acc[3][0]); \
        acc[0][1] = mfma16(q0, af1, acc[0][1]); acc[1][1] = mfma16(q1, af1, acc[1][1]); \
        acc[2][1] = mfma16(q2, af1, acc[2][1]); acc[3][1] = mfma16(q3, af1, acc[3][1]); \
        acc[0][2] = mfma16(q0, af2, acc[0][2]); acc[1][2] = mfma16(q1, af2, acc[1][2]); \
        acc[2][2] = mfma16(q2, af2, acc[2][2]); acc[3][2] = mfma16(q3, af2, acc[3][2]); \
        acc[0][3] = mfma16(q0, af3, acc[0][3]); acc[1][3] = mfma16(q1, af3, acc[1][3]); \
        acc[2][3] = mfma16(q2, af3, acc[2][3]); acc[3][3] = mfma16(q3, af3, acc[3][3]); \
    } else { \
        acc[0][0] = mfma16(af0, q0, acc[0][0]); acc[0][1] = mfma16(af0, q1, acc[0][1]); \
        acc[0][2] = mfma16(af0, q2, acc[0][2]); acc[0][3] = mfma16(af0, q3, acc[0][3]); \
        acc[1][0] = mfma16(af1, q0, acc[1][0]); acc[1][1] = mfma16(af1, q1, acc[1][1]); \
        acc[1][2] = mfma16(af1, q2, acc[1][2]); acc[1][3] = mfma16(af1, q3, acc[1][3]); \
        acc[2][0] = mfma16(af2, q0, acc[2][0]); acc[2][1] = mfma16(af2, q1, acc[2][1]); \
        acc[2][2] = mfma16(af2, q2, acc[2][2]); acc[2][3] = mfma16(af2, q3, acc[2][3]); \
        acc[3][0] = mfma16(af3, q0, acc[3][0]); acc[3][1] = mfma16(af3, q1, acc[3][1]); \
        acc[3][2] = mfma16(af3, q2, acc[3][2]); acc[3][3] = mfma16(af3, q3, acc[3][3]); \
    }

#define TILE_(CA, CB, NA, NB, KBN, STG) { \
    { /* phase 0: k-slice 0 */ \
        s16x8 q0 = LDB_(CB,0,0), q1 = LDB_(CB,0,1), q2 = LDB_(CB,0,2), q3 = LDB_(CB,0,3); \
        s16x8 af0 = LDA_(CA,0,0), af1 = LDA_(CA,0,1), af2 = LDA_(CA,0,2), af3 = LDA_(CA,0,3); \
        if (STG) { STA_(NA, KBN, 0); STA_(NA, KBN, 1); STB_(NB, KBN, 0); } \
        MEMF; SBAR; \
        __builtin_amdgcn_s_setprio(1); MMGRP16; __builtin_amdgcn_s_setprio(0); \
        if (STG) { asm volatile("s_waitcnt vmcnt(3)" ::: "memory"); } \
        else     { asm volatile("s_waitcnt vmcnt(0)" ::: "memory"); } \
        MEMF; SBAR; MEMF; \
    } \
    { /* phase 1: k-slice 1 */ \
        s16x8 q0 = LDB_(CB,1,0), q1 = LDB_(CB,1,1), q2 = LDB_(CB,1,2), q3 = LDB_(CB,1,3); \
        s16x8 af0 = LDA_(CA,1,0), af1 = LDA_(CA,1,1), af2 = LDA_(CA,1,2), af3 = LDA_(CA,1,3); \
        if (STG) { STA_(NA, KBN, 2); STA_(NA, KBN, 3); STB_(NB, KBN, 1); } \
        MEMF; SBAR; \
        __builtin_amdgcn_s_setprio(1); MMGRP16; __builtin_amdgcn_s_setprio(0); \
        if (STG) { asm volatile("s_waitcnt vmcnt(3)" ::: "memory"); } \
        MEMF; SBAR; MEMF; \
    } \
}

template<bool SWAP>
__device__ __forceinline__ void gemm8p_core(const unsigned short* __restrict__ A,
                                            const unsigned short* __restrict__ Bw,
                                            int mBase, int nBase,
                                            f32x4 (&acc)[4][4], char* lds)
{
    const int tid = threadIdx.x;
    const int w = tid >> 6, l = tid & 63;
    const int lg = l >> 4, lr = l & 15;
    const int wm = w & 3, wn = w >> 2;
    char* const A0 = lds;
    char* const A1 = lds + 32768;
    char* const B0 = lds + 65536;
    char* const B1 = lds + 81920;
    const int wbase = w * 1024;
    const int rdsw = (lr >> 2) & 1;                 // read-side swizzle bit (row bit2)
    const int swz  = (tid >> 3) & 1;                // stage-side: row bit2
    const int skh  = (tid & 1) ^ swz;               // pre-swizzled k-octet
    const unsigned short* Ag = A  + (size_t)(mBase + (tid >> 1)) * EMB + skh * 8;
    const unsigned short* Bg = Bw + (size_t)(nBase + ((tid >> 1) & 127)) * EMB
                                  + (tid >> 8) * 16 + skh * 8;

    // prologue: stage tile 0 (order: A0,A1,B0 | A2,A3,B1), wait for group1 only
    STA_(A0, 0, 0); STA_(A0, 0, 1); STB_(B0, 0, 0);
    STA_(A0, 0, 2); STA_(A0, 0, 3); STB_(B0, 0, 1);
    asm volatile("s_waitcnt vmcnt(3)" ::: "memory");
    SBAR; MEMF;

    for (int t = 0; t < 16; t += 2) {
        TILE_(A0, B0, A1, B1, (t+1)*64, true);
        TILE_(A1, B1, A0, B0, (t+2)*64, (t+2) < 16);
    }
}

// ---------------- fused QKV GEMM ----------------
// grid (24, 32): x = seg*8 + n-tile(128), y = m-tile(256).
__global__ __launch_bounds__(512) void gemm_qkv8(const unsigned short* __restrict__ A,
                                                 const unsigned short* __restrict__ wqb,
                                                 const unsigned short* __restrict__ wkb,
                                                 const unsigned short* __restrict__ wvb,
                                                 const float* __restrict__ bq,
                                                 const float* __restrict__ bk,
                                                 const float* __restrict__ bv,
                                                 unsigned short* __restrict__ qB,
                                                 unsigned short* __restrict__ kB,
                                                 unsigned short* __restrict__ vtB) {
    __shared__ __align__(16) char lds[98304];
    const int nb  = blockIdx.x;
    const int seg = nb >> 3;
    const int mBase = blockIdx.y * 256;
    const int nBase = (nb & 7) * 128;
    const unsigned short* Bw = (seg == 0) ? wqb : (seg == 1) ? wkb : wvb;
    const float* bias = (seg == 0) ? bq : (seg == 1) ? bk : bv;

    const int tid = threadIdx.x;
    const int w = tid >> 6, l = tid & 63;
    const int lg = l >> 4, lr = l & 15;
    const int wm = w & 3, wn = w >> 2;

    f32x4 acc[4][4] = {};
    if (seg == 2) gemm8p_core<true >(A, Bw, mBase, nBase, acc, lds);
    else          gemm8p_core<false>(A, Bw, mBase, nBase, acc, lds);

    const int colBase = nBase + wn * 64;
    const int rowBase = mBase + wm * 64;
    if (seg != 2) {
        unsigned short* outp = seg ? kB : qB;
        const float oscale = seg ? 1.0f : QSCALE;
        #pragma unroll
        for (int ni = 0; ni < 4; ++ni) {
            const int col = colBase + ni*16 + lr;
            const float bv = bias[col];
            const int h = col >> 6, d = col & 63;
            const int inner = ((d >> 4) * 2 + ((d >> 3) & 1)) * 256 + (d & 7);
            #pragma unroll
            for (int mi = 0; mi < 4; ++mi) {
                #pragma unroll
                for (int r = 0; r < 4; ++r) {
                    const int gr = rowBase + mi*16 + lg*4 + r;
                    const int b = gr >> 11, sin_ = gr & 2047;
                    const int strip = sin_ >> 5, l31q = sin_ & 31;
                    outp[(size_t)(b*NH + h) * (SEQ*DHEAD) + strip*2048 + inner + l31q*8]
                        = f2bf((acc[mi][ni][r] + bv) * oscale);
                }
            }
        }
    } else {
        #pragma unroll
        for (int ni = 0; ni < 4; ++ni) {
            #pragma unroll
            for (int r = 0; r < 4; ++r) {
                const int n = colBase + ni*16 + lg*4 + r;
                const float bv = bias[n];
                const int h = n >> 6, d = n & 63;
                #pragma unroll
                for (int mi = 0; mi < 4; ++mi) {
                    const int tok = rowBase + mi*16 + lr;
                    const int b = tok >> 11, sv = tok & 2047;
                    const int kvt = sv >> 5, ks = (sv >> 4) & 1, hi2 = (sv >> 3) & 1, j = sv & 7;
                    vtB[(size_t)(b*NH + h) * (SEQ*DHEAD) + kvt*2048 + (ks*2 + hi2)*512 + d*8 + j]
                        = f2bf(acc[ni][mi][r] + bv);
                }
            }
        }
    }
}

// ---------------- output projection GEMM (fp32 out + bias) ----------------
// grid (8, 32) = 256 blocks = exactly one CU round.
__global__ __launch_bounds__(512) void gemm_out8(const unsigned short* __restrict__ A,
                                                 const unsigned short* __restrict__ Bw,
                                                 const float* __restrict__ bias,
                                                 float* __restrict__ Out) {
    __shared__ __align__(16) char lds[98304];
    const int mBase = blockIdx.y * 256;
    const int nBase = blockIdx.x * 128;
    const int tid = threadIdx.x;
    const int w = tid >> 6, l = tid & 63;
    const int lg = l >> 4, lr = l & 15;
    const int wm = w & 3, wn = w >> 2;

    f32x4 acc[4][4] = {};
    gemm8p_core<false>(A, Bw, mBase, nBase, acc, lds);

    const int colBase = nBase + wn * 64;
    const int rowBase = mBase + wm * 64;
    #pragma unroll
    for (int ni = 0; ni < 4; ++ni) {
        const int col = colBase + ni*16 + lr;
        const float bv = bias[col];
        #pragma unroll
        for (int mi = 0; mi < 4; ++mi) {
            #pragma unroll
            for (int r = 0; r < 4; ++r) {
                const int gr = rowBase + mi*16 + lg*4 + r;
                Out[(size_t)gr * EMB + col] = acc[mi][ni][r] + bv;
            }
        }
    }
}

// ---------------- flash attention (causal), swapped-operand 32x32 MFMA ----------------
__global__ __launch_bounds__(64) void attn_fwd(const unsigned short* __restrict__ qb,
                                               const unsigned short* __restrict__ kb,
                                               const unsigned short* __restrict__ vb,
                                               unsigned short* __restrict__ ctx) {
    __shared__ __align__(16) unsigned sld[32*36];
    const int l = threadIdx.x;
    const int l31 = l & 31, hi = l >> 5;
    const int bh = blockIdx.x & 63;
    const int strip = (NSTRIP - 1) - ((int)blockIdx.x >> 6);   // mixes depth across CUs
    const int q0 = strip * 32;
    const size_t hbase = (size_t)bh * SEQ * DHEAD;
    const unsigned short* qh = qb + hbase;
    const unsigned short* kh = kb + hbase;
    const unsigned short* vh = vb + hbase;

    s16x8 qf[4];
    #pragma unroll
    for (int s = 0; s < 4; ++s)
        qf[s] = *reinterpret_cast<const s16x8*>(&qh[strip*2048 + s*512 + l*8]);

    f32x16 o0 = {}, o1 = {};
    float m = -__builtin_inff(), lsum = 0.f;
    const int ntiles = strip + 1;

    s16x8 kfA[4], vfA[4], kfB[4], vfB[4];

    auto LOADKV = [&](s16x8* kf, s16x8* vf, int t) {
        const unsigned short* kp = kh + t*2048;
        #pragma unroll
        for (int s = 0; s < 4; ++s)
            kf[s] = *reinterpret_cast<const s16x8*>(&kp[s*512 + l*8]);
        const unsigned short* vp = vh + t*2048 + hi*512 + l31*8;
        #pragma unroll
        for (int ks = 0; ks < 2; ++ks) {
            vf[ks]     = *reinterpret_cast<const s16x8*>(&vp[ks*1024]);
            vf[2 + ks] = *reinterpret_cast<const s16x8*>(&vp[ks*1024 + 256]);
        }
    };

    auto BODY = [&](s16x8* kf, s16x8* vf, int t) {
        f32x16 sa = {};
        #pragma unroll
        for (int s = 0; s < 4; ++s) sa = mfma32(kf[s], qf[s], sa);

        if (t == strip) {  // diagonal tile: mask kv > q
            #pragma unroll
            for (int r = 0; r < 16; ++r) {
                const int kvloc = (r & 3) + 8*(r >> 2) + 4*hi;
                if (kvloc > l31) sa[r] = -__builtin_inff();
            }
        }

        const float a0 = max3f(sa[0],  sa[1],  sa[2]);
        const float a1 = max3f(sa[3],  sa[4],  sa[5]);
        const float a2 = max3f(sa[6],  sa[7],  sa[8]);
        const float a3 = max3f(sa[9],  sa[10], sa[11]);
        const float a4 = max3f(sa[12], sa[13], sa[14]);
        const float b0 = max3f(a0, a1, a2);
        const float b1 = max3f(a3, a4, sa[15]);
        float pm = fmaxf(b0, b1);
        pm = fmaxf(pm, __shfl_xor(pm, 32));

        float mn = m;
        if (!__all(pm <= m + 8.0f)) {        // T13 defer-max (log2 domain: p <= 256)
            mn = fmaxf(m, pm);
            const float fs = exp2r(m - mn);
            o0 *= fs; o1 *= fs; lsum *= fs;
            m = mn;
        }

        #pragma unroll
        for (int r = 0; r < 16; ++r) sa[r] = exp2r(sa[r] - mn);   // in-place

        const float s0 = sa[0]+sa[1],   s1 = sa[2]+sa[3],   s2 = sa[4]+sa[5],   s3 = sa[6]+sa[7];
        const float s4 = sa[8]+sa[9],   s5 = sa[10]+sa[11], s6 = sa[12]+sa[13], s7 = sa[14]+sa[15];
        const float t0 = s0+s1, t1 = s2+s3, t2 = s4+s5, t3 = s6+s7;
        float rs = (t0+t1) + (t2+t3);
        rs += __shfl_xor(rs, 32);
        lsum += rs;

        unsigned u[4], v[4];
        #pragma unroll
        for (int r2 = 0; r2 < 4; ++r2) {
            u[r2] = cvtpk(sa[4*r2 + 0], sa[4*r2 + 1]);
            v[r2] = cvtpk(sa[4*r2 + 2], sa[4*r2 + 3]);
        }
        plane_swap(u[0], u[1]); plane_swap(v[0], v[1]);
        plane_swap(u[2], u[3]); plane_swap(v[2], v[3]);
        const s16x8 pf0 = frag4(u[0], v[0], u[1], v[1]);
        const s16x8 pf1 = frag4(u[2], v[2], u[3], v[3]);

        o0 = mfma32(vf[0], pf0, o0);
        o0 = mfma32(vf[1], pf1, o0);
        o1 = mfma32(vf[2], pf0, o1);
        o1 = mfma32(vf[3], pf1, o1);
    };

    LOADKV(kfA, vfA, 0);
    int t = 0;
    for (; t + 1 < ntiles; t += 2) {
        LOADKV(kfB, vfB, t + 1);
        BODY(kfA, vfA, t);
        if (t + 2 < ntiles) LOADKV(kfA, vfA, t + 2);
        BODY(kfB, vfB, t + 1);
    }
    if (t < ntiles) BODY(kfA, vfA, t);

    const float inv = 1.0f / lsum;
    #pragma unroll
    for (int dt = 0; dt < 2; ++dt) {
        #pragma unroll
        for (int r2 = 0; r2 < 4; ++r2) {
            const float e0 = (dt ? o1[4*r2+0] : o0[4*r2+0]) * inv;
            const float e1 = (dt ? o1[4*r2+1] : o0[4*r2+1]) * inv;
            const float e2 = (dt ? o1[4*r2+2] : o0[4*r2+2]) * inv;
            const float e3 = (dt ? o1[4*r2+3] : o0[4*r2+3]) * inv;
            const int col = 4*r2 + 2*hi + 16*dt;
            sld[l31*36 + col]     = cvtpk(e0, e1);
            sld[l31*36 + col + 1] = cvtpk(e2, e3);
        }
    }
    asm volatile("s_waitcnt lgkmcnt(0)" ::: "memory");
    __builtin_amdgcn_sched_barrier(0);
    const int row = l >> 1, half = l & 1;
    const unsigned* rp = &sld[row*36 + half*16];
    const int b = bh >> 4, h = bh & 15;
    unsigned short* op = &ctx[((size_t)b*SEQ + q0 + row) * EMB + h*DHEAD + half*32];
    #pragma unroll
    for (int i = 0; i < 4; ++i) {
        uint4 d4 = *reinterpret_cast<const uint4*>(rp + i*4);
        *reinterpret_cast<uint4*>(op + i*8) = d4;
    }
}

// ---------------- launch ----------------
extern "C" void kernel_launch(void* const* d_in, const int* in_sizes, int n_in,
                              void* d_out, int out_size, void* d_ws, size_t ws_size,
                              hipStream_t stream) {
    const float* x  = (const float*)d_in[0];
    const float* wq = (const float*)d_in[1];
    const float* bq = (const float*)d_in[2];
    const float* wk = (const float*)d_in[3];
    const float* bk = (const float*)d_in[4];
    const float* wv = (const float*)d_in[5];
    const float* bv = (const float*)d_in[6];
    const float* wo = (const float*)d_in[7];
    const float* bo = (const float*)d_in[8];
    float* out = (float*)d_out;

    char* ws = (char*)d_ws;
    const size_t MB = 1ull << 20;
    unsigned short* xb  = (unsigned short*)(ws);            // 16 MB; reused as ctx later
    unsigned short* wqb = (unsigned short*)(ws + 16*MB);
    unsigned short* wkb = (unsigned short*)(ws + 18*MB);
    unsigned short* wvb = (unsigned short*)(ws + 20*MB);
    unsigned short* wob = (unsigned short*)(ws + 22*MB);
    unsigned short* qB  = (unsigned short*)(ws + 24*MB);    // fragment-ready, pre-scaled (exp2 domain)
    unsigned short* kB  = (unsigned short*)(ws + 40*MB);    // fragment-ready
    unsigned short* vtB = (unsigned short*)(ws + 56*MB);    // fragment-ready V^T
    unsigned short* ctx = xb;

    const int nx4 = MROWS * EMB / 4;
    const int nw4 = EMB * EMB / 4;
    cvt_bf16<<<(nx4 + 255)/256, 256, 0, stream>>>(x, xb, nx4);
    cvt_bf16_w<<<dim3((nw4 + 255)/256, 4), 256, 0, stream>>>(wq, wk, wv, wo, wqb, wkb, wvb, wob, nw4);

    gemm_qkv8<<<dim3(24, MROWS/256), 512, 0, stream>>>(xb, wqb, wkb, wvb, bq, bk, bv, qB, kB, vtB);

    attn_fwd<<<dim3(NSTRIP * BATCH * NH), 64, 0, stream>>>(qB, kB, vtB, ctx);

    gemm_out8<<<dim3(EMB/128, MROWS/256), 512, 0, stream>>>(ctx, wob, bo, out);
}